// Round 9
// baseline (432.753 us; speedup 1.0000x reference)
//
#include <hip/hip_runtime.h>
#include <cstdint>
#include <cstddef>

// DeepseekV3 MoE on gfx950.
// R8->R9 (R8: flat 418.8; gateup Occupancy 13-17% = ~1 wave/SIMD = ZERO TLP;
// 3 pipeline-depth rounds all flat -> stall is not load-latency depth, it's
// no concurrent waves to hide ANY stall):
// (1) GEMM N-block 128->64: grid 896->1792 blocks, LDS/buf 24->16KB (gateup)
// 16->12KB (down), acc halves -> ~95 VGPR, __launch_bounds__(256,4) ->
// 4 blocks/CU co-resident (16 waves/CU, 4/SIMD). Independent blocks give
// cross-block TLP that the 8-wave lockstep never had. MFMA:ds_read ratio
// per wave unchanged; extra A-panel re-reads hit L3-resident xb/act (4MB).
// (2) T5 setprio(1) around MFMA clusters: with multiple independent blocks
// per CU there are waves at different phases to arbitrate (m191 mechanism).
// (3) counted-vmcnt 2-buf schedule kept; stage = 4 loads (gateup: A x2,
// Bg x1, Bu x1) -> vmcnt(4); down stage = 3 -> vmcnt(3).
// Transposes unchanged from R8 (three shapes all ~88us -> shape-insensitive;
// structural elimination is the next lever if GEMMs respond).

#define T_TOK 2048
#define DIM   1024
#define NEXP  16
#define MAXTILES 80
#define SH_TILES 32
#define GRID_Y (MAXTILES + SH_TILES)
#define NBLK2 (16 * GRID_Y)      // 1792 = 8 XCDs * 224 (bijective swizzle)
#define ABASE_SH 10240           // act row where shared-expert rows start

typedef __bf16 bf16x8_t __attribute__((ext_vector_type(8)));
typedef float  f32x4_t  __attribute__((ext_vector_type(4)));
typedef unsigned short ushort8_t __attribute__((ext_vector_type(8)));
typedef unsigned short ushort4_t __attribute__((ext_vector_type(4)));

// ---- workspace layout (bytes) ----
#define OFF_XB     (0UL)            // 4 MB   (dead after k_gateup)
#define OFF_SHGT   (4UL<<20)        // 4 MB   [2048][1024] (dead after k_gateup)
#define OFF_SHUT   (8UL<<20)        // 4 MB
#define OFF_GATET  (12UL<<20)       // 32 MB  [E][F][D] (dead after k_gateup)
#define OFF_UPT    (44UL<<20)       // 32 MB
#define OFF_DOWNT  (76UL<<20)       // 32 MB  [E][D][F]
#define OFF_SHDT   (108UL<<20)      // 4 MB   [1024][2048]
#define OFF_ACT    (112UL<<20)      // 28 MB  (14336 rows x 1024 bf16)
#define OFF_YSLOT  (140UL<<20)      // 20 MB  (10240 rows x 1024 bf16)
#define OFF_PART   (0UL)            // 16 MB  fp32 2 slabs, overlays XB/SHGT/SHUT/GATET-head
#define OFF_CTRL   (160UL<<20)
#define CT_OFFSETS  128
#define CT_NTILES   192
#define CT_TILEEXP  256
#define CT_SLOTTOK  4096
#define CT_TKSLOT   49152
#define CT_TOPKIDX  81920
#define CT_TOPKW    114688

__device__ __forceinline__ unsigned short f2bf(float f) {
  __bf16 h = (__bf16)f;
  return __builtin_bit_cast(unsigned short, h);
}
__device__ __forceinline__ float bf2f(unsigned short u) {
  unsigned int v = ((unsigned int)u) << 16;
  return __builtin_bit_cast(float, v);
}
__device__ __forceinline__ void gld16(const void* g, void* l) {
  __builtin_amdgcn_global_load_lds(
      (const __attribute__((address_space(1))) void*)(g),
      (__attribute__((address_space(3))) void*)(l), 16, 0, 0);
}

// counted-vmcnt barrier primitives (T4): wait own oldest loads, then raw
// barrier (NO full drain), then pin the scheduler (rule #18 insurance).
#define VWAIT4 asm volatile("s_waitcnt vmcnt(4)" ::: "memory")
#define VWAIT3 asm volatile("s_waitcnt vmcnt(3)" ::: "memory")
#define VWAIT0 asm volatile("s_waitcnt vmcnt(0)" ::: "memory")
#define BAR { __builtin_amdgcn_s_barrier(); __builtin_amdgcn_sched_barrier(0); }

// ---- transpose + convert body: src fp32 [R][C] -> dst bf16 [C][R] ----
// 128x128 tile per block; all 16 float4 loads issued before LDS writes.
__device__ __forceinline__ void tbody(const float* __restrict__ src,
                                      unsigned short* __restrict__ dst,
                                      int R, int C) {
  __shared__ unsigned short tile[128 * 132];
  int cT = blockIdx.x * 128, rT = blockIdx.y * 128;
  int t = threadIdx.x;
  int rb = t >> 5, cb = t & 31;          // rb in [0,8), cb in [0,32)
  float f[4][4][4];                      // [pass][i][j]
#pragma unroll
  for (int p = 0; p < 4; p++)
#pragma unroll
    for (int i = 0; i < 4; i++) {
      float4 v = *(const float4*)(src + (long)(rT + p * 32 + 4 * rb + i) * C + cT + 4 * cb);
      f[p][i][0] = v.x; f[p][i][1] = v.y; f[p][i][2] = v.z; f[p][i][3] = v.w;
    }
#pragma unroll
  for (int p = 0; p < 4; p++)
#pragma unroll
    for (int j = 0; j < 4; j++) {
      ushort4_t o;
      o[0] = f2bf(f[p][0][j]); o[1] = f2bf(f[p][1][j]);
      o[2] = f2bf(f[p][2][j]); o[3] = f2bf(f[p][3][j]);
      *(ushort4_t*)&tile[(4 * cb + j) * 132 + p * 32 + 4 * rb] = o;
    }
  __syncthreads();
#pragma unroll
  for (int m = 0; m < 8; m++) {
    int q = t + 256 * m;
    int c = q >> 4, r0 = (q & 15) * 8;
    ushort4_t lo = *(const ushort4_t*)&tile[c * 132 + r0];
    ushort4_t hi = *(const ushort4_t*)&tile[c * 132 + r0 + 4];
    ushort8_t w8 = {lo[0], lo[1], lo[2], lo[3], hi[0], hi[1], hi[2], hi[3]};
    *(ushort8_t*)(dst + (long)(cT + c) * R + rT + r0) = w8;
  }
}

// generic (used for sh_down): z = batch index
__global__ void k_transpose(const float* __restrict__ src, unsigned short* __restrict__ dst,
                            int R, int C) {
  long b = blockIdx.z;
  tbody(src + b * (long)R * C, dst + b * (long)R * C, R, C);
}

// fused gate/up/down expert-weight transpose: grid (8,8,48), z>>4 selects weight
__global__ void k_transpose3(const float* __restrict__ g, const float* __restrict__ u,
                             const float* __restrict__ d, unsigned short* __restrict__ gT,
                             unsigned short* __restrict__ uT, unsigned short* __restrict__ dT) {
  int z = blockIdx.z;
  int which = z >> 4;
  long b = z & 15;
  const float* s = (which == 0) ? g : (which == 1) ? u : d;
  unsigned short* t = (which == 0) ? gT : (which == 1) ? uT : dT;
  tbody(s + b * 1048576L, t + b * 1048576L, 1024, 1024);
}

// fused shared gate/up transpose: grid (16,8,2)
__global__ void k_transpose_sh(const float* __restrict__ sg, const float* __restrict__ su,
                               unsigned short* __restrict__ gT, unsigned short* __restrict__ uT) {
  const float* s = blockIdx.z ? su : sg;
  unsigned short* t = blockIdx.z ? uT : gT;
  tbody(s, t, 1024, 2048);
}

// ---- router: 1 block per token; also emits xb (bf16 x) ----
__global__ __launch_bounds__(256) void k_router(
    const float* __restrict__ x, const float* __restrict__ rw,
    const float* __restrict__ bias, int* __restrict__ topk_idx,
    float* __restrict__ topk_w, unsigned short* __restrict__ xb) {
  int t = blockIdx.x, tid = threadIdx.x;
  int wv = tid >> 6, lane = tid & 63;
  float4 xv = ((const float4*)(x + (size_t)t * DIM))[tid];
  // fused fp32 -> bf16 conversion of x (replaces k_cvt)
  ushort4_t xo;
  xo[0] = f2bf(xv.x); xo[1] = f2bf(xv.y); xo[2] = f2bf(xv.z); xo[3] = f2bf(xv.w);
  ((ushort4_t*)(xb + (size_t)t * DIM))[tid] = xo;
  float part[NEXP];
#pragma unroll
  for (int e = 0; e < NEXP; e++) {
    float4 wr = ((const float4*)(rw + (size_t)e * DIM))[tid];
    part[e] = xv.x * wr.x + xv.y * wr.y + xv.z * wr.z + xv.w * wr.w;
  }
  __shared__ float wsum_s[4 * NEXP];
#pragma unroll
  for (int e = 0; e < NEXP; e++) {
    float v = part[e];
#pragma unroll
    for (int off = 32; off; off >>= 1) v += __shfl_xor(v, off, 64);
    if (lane == 0) wsum_s[wv * NEXP + e] = v;
  }
  __syncthreads();
  if (tid == 0) {
    float r_sc[NEXP], r_s[NEXP];
#pragma unroll
    for (int e = 0; e < NEXP; e++) {
      float logit = wsum_s[e] + wsum_s[NEXP + e] + wsum_s[2 * NEXP + e] +
                    wsum_s[3 * NEXP + e];
      float sc = 1.f / (1.f + expf(-logit));
      r_sc[e] = sc;
      r_s[e] = sc + bias[e];
    }
    float gs[4];
#pragma unroll
    for (int g = 0; g < 4; g++) {
      float m1 = -1e30f, m2 = -1e30f;
#pragma unroll
      for (int j = 0; j < 4; j++) {
        float v = r_s[g * 4 + j];
        if (v > m1) { m2 = m1; m1 = v; } else if (v > m2) m2 = v;
      }
      gs[g] = m1 + m2;
    }
    int g1 = 0;
    for (int g = 1; g < 4; g++) if (gs[g] > gs[g1]) g1 = g;
    int g2 = -1;
    for (int g = 0; g < 4; g++) { if (g == g1) continue; if (g2 < 0 || gs[g] > gs[g2]) g2 = g; }
    int taken = 0, idx[4];
    float w[4], wsum = 1e-20f;
#pragma unroll
    for (int k = 0; k < 4; k++) {
      float best = -1e30f; int bi = 0;
#pragma unroll
      for (int e2 = 0; e2 < 16; e2++) {
        if (taken & (1 << e2)) continue;
        int g = e2 >> 2;
        float v = (g == g1 || g == g2) ? r_s[e2] : -1.f;
        if (v > best) { best = v; bi = e2; }
      }
      taken |= 1 << bi; idx[k] = bi;
    }
#pragma unroll
    for (int k = 0; k < 4; k++) { w[k] = r_sc[idx[k]]; wsum += w[k]; }
    float sc2 = 2.5f / wsum;
#pragma unroll
    for (int k = 0; k < 4; k++) {
      topk_idx[t * 4 + k] = idx[k];
      topk_w[t * 4 + k] = w[k] * sc2;
    }
  }
}

// ---- route_post: single block, atomic-free count + scan + scatter ----
__global__ __launch_bounds__(256) void k_route_post(
    const int* __restrict__ topk_idx, int* __restrict__ offsets,
    int* __restrict__ tile_expert, int* __restrict__ n_tiles,
    int* __restrict__ slot_token, int* __restrict__ tk_slot) {
  __shared__ int cnt[NEXP][257];
  __shared__ int offs[NEXP], tot[NEXP];
  int tid = threadIdx.x;
  int4 ent[8];
#pragma unroll
  for (int i = 0; i < 8; i++) ent[i] = ((const int4*)topk_idx)[tid * 8 + i];
  int lc[NEXP];
#pragma unroll
  for (int j = 0; j < NEXP; j++) lc[j] = 0;
#pragma unroll
  for (int i = 0; i < 8; i++) {
    int es[4] = {ent[i].x, ent[i].y, ent[i].z, ent[i].w};
#pragma unroll
    for (int k = 0; k < 4; k++)
#pragma unroll
      for (int j = 0; j < NEXP; j++) lc[j] += (es[k] == j) ? 1 : 0;
  }
#pragma unroll
  for (int j = 0; j < NEXP; j++) cnt[j][tid] = lc[j];
  __syncthreads();
  if (tid < NEXP) {
    int base = 0;
    for (int c = 0; c < 256; c += 8) {
      int v[8];
#pragma unroll
      for (int i = 0; i < 8; i++) v[i] = cnt[tid][c + i];
#pragma unroll
      for (int i = 0; i < 8; i++) { cnt[tid][c + i] = base; base += v[i]; }
    }
    tot[tid] = base;
  }
  __syncthreads();
  if (tid == 0) {
    int cum = 0, tt = 0;
    for (int e = 0; e < NEXP; e++) {
      offs[e] = cum;
      offsets[e] = cum;
      int nt = (tot[e] + 127) >> 7;
      for (int i = 0; i < nt; i++) tile_expert[tt++] = e;
      cum += nt << 7;
    }
    n_tiles[0] = tt;
  }
  __syncthreads();
  for (int e = 0; e < NEXP; e++) {
    int s0 = offs[e] + tot[e];
    int s1 = offs[e] + (((tot[e] + 127) >> 7) << 7);
    for (int s = s0 + tid; s < s1; s += 256) slot_token[s] = -1;
  }
  int lcur[NEXP];
#pragma unroll
  for (int j = 0; j < NEXP; j++) lcur[j] = offs[j] + cnt[j][tid];
#pragma unroll
  for (int i = 0; i < 8; i++) {
    int t = tid * 8 + i;
    int es[4] = {ent[i].x, ent[i].y, ent[i].z, ent[i].w};
#pragma unroll
    for (int k = 0; k < 4; k++) {
      int e = es[k], pos = 0;
#pragma unroll
      for (int j = 0; j < NEXP; j++) pos += (e == j) ? lcur[j] : 0;
#pragma unroll
      for (int j = 0; j < NEXP; j++) lcur[j] += (e == j) ? 1 : 0;
      slot_token[pos] = t;
      tk_slot[t * 4 + k] = pos;
    }
  }
}

// ---- fused gate+up+silu GEMM: 128m x 64n blocks, 4 blocks/CU ----
// 1D grid 1792, XCD-swizzled: wk=(o&7)*224+(o>>3); bt=wk>>4, nx=wk&15.
__global__ __launch_bounds__(256, 4) void k_gateup(
    const unsigned short* __restrict__ xb, const unsigned short* __restrict__ gateT,
    const unsigned short* __restrict__ upT, const unsigned short* __restrict__ shGT,
    const unsigned short* __restrict__ shUT, unsigned short* __restrict__ act,
    const int* __restrict__ slot_token, const int* __restrict__ tile_expert,
    const int* __restrict__ n_tiles) {
  int o = blockIdx.x;
  int wk = (o & 7) * (2 * GRID_Y) + (o >> 3);   // bijective (1792 % 8 == 0)
  int nx = wk & 15, bt = wk >> 4;
  int NT = n_tiles[0];
  bool routed = bt < NT;
  const unsigned short *Bg, *Bu;
  int actbase, tokbase = 0;
  if (routed) {
    int e = tile_expert[bt];
    Bg = gateT + ((size_t)e << 20);
    Bu = upT + ((size_t)e << 20);
    actbase = bt * 128;
  } else {
    int st = bt - NT;
    if (st >= SH_TILES) return;
    int se = st >> 4, tt = st & 15;
    Bg = shGT + ((size_t)se << 20);
    Bu = shUT + ((size_t)se << 20);
    actbase = ABASE_SH + se * T_TOK + tt * 128;
    tokbase = tt * 128;
  }
  int n0 = nx * 64;

  // [2 bufs][A(8KB) | Bg(4KB) | Bu(4KB)] = 32 KB total -> 4 blocks/CU
  __shared__ unsigned short lds[2 * 8192];

  int tid = threadIdx.x;
  int w = tid >> 6, L = tid & 63;
  // A staging: 128 rows x 4 chunks over 512 slots (2 loads/thread)
  int c0 = w * 128 + L, c1 = c0 + 64;
  int ar0 = c0 >> 2, ar1 = c1 >> 2;
  int ch0 = (c0 & 3) ^ (ar0 & 3), ch1 = (c1 & 3) ^ (ar1 & 3);
  long arow0, arow1;
  if (routed) {
    int t0 = slot_token[bt * 128 + ar0]; if (t0 < 0) t0 = 0;
    int t1 = slot_token[bt * 128 + ar1]; if (t1 < 0) t1 = 0;
    arow0 = t0; arow1 = t1;
  } else {
    arow0 = tokbase + ar0; arow1 = tokbase + ar1;
  }
  // B staging: 64 rows x 4 chunks over 256 slots (1 load/thread per matrix)
  int arb = tid >> 2;
  int chb = (tid & 3) ^ (arb & 3);
  const char* aA = (const char*)(xb + arow0 * 1024) + ch0 * 16;
  const char* aB = (const char*)(xb + arow1 * 1024) + ch1 * 16;
  const char* gA = (const char*)(Bg + (size_t)(n0 + arb) * 1024) + chb * 16;
  const char* uA = (const char*)(Bu + (size_t)(n0 + arb) * 1024) + chb * 16;
  // byte offsets within a buffer: A at 0, Bg at 8192, Bu at 12288
  const int a0o = w * 2048, a1o = w * 2048 + 1024;
  const int gBo = 8192 + w * 1024;
  const int uBo = 12288 + w * 1024;

  f32x4_t accg[4][2], accu[4][2];
#pragma unroll
  for (int i = 0; i < 4; i++)
#pragma unroll
    for (int j = 0; j < 2; j++) {
      accg[i][j] = f32x4_t{0.f, 0.f, 0.f, 0.f};
      accu[i][j] = f32x4_t{0.f, 0.f, 0.f, 0.f};
    }

  int mb = (w >> 1) * 64, nb = (w & 1) * 32;
  int lr = L & 15, quad = L >> 4;
  int sw = ((quad ^ (lr & 3)) << 3);

#define GU_STAGE(BOFF)                                                       \
  { char* bp = (char*)lds + (BOFF);                                          \
    gld16(aA, bp + a0o); gld16(aB, bp + a1o);                                \
    gld16(gA, bp + gBo); gld16(uA, bp + uBo);                                \
    aA += 64; aB += 64; gA += 64; uA += 64; }

#define GU_COMPUTE(UOFF)                                                     \
  { const unsigned short* pA = lds + (UOFF);                                 \
    const unsigned short* pG = pA + 4096;                                    \
    const unsigned short* pU = pA + 6144;                                    \
    bf16x8_t af[4], bg[2], bu[2];                                            \
    _Pragma("unroll")                                                        \
    for (int i = 0; i < 4; i++) af[i] = *(const bf16x8_t*)(pA + (mb + 16 * i + lr) * 32 + sw); \
    _Pragma("unroll")                                                        \
    for (int j = 0; j < 2; j++) bg[j] = *(const bf16x8_t*)(pG + (nb + 16 * j + lr) * 32 + sw); \
    _Pragma("unroll")                                                        \
    for (int j = 0; j < 2; j++) bu[j] = *(const bf16x8_t*)(pU + (nb + 16 * j + lr) * 32 + sw); \
    __builtin_amdgcn_s_setprio(1);                                           \
    _Pragma("unroll")                                                        \
    for (int i = 0; i < 4; i++)                                              \
      _Pragma("unroll")                                                      \
      for (int j = 0; j < 2; j++) {                                          \
        accg[i][j] = __builtin_amdgcn_mfma_f32_16x16x32_bf16(af[i], bg[j], accg[i][j], 0, 0, 0); \
        accu[i][j] = __builtin_amdgcn_mfma_f32_16x16x32_bf16(af[i], bu[j], accu[i][j], 0, 0, 0); \
      }                                                                      \
    __builtin_amdgcn_s_setprio(0); }

  // 2-buf counted-vmcnt: stage = 4 loads; vmcnt(4) leaves next buf in flight
  GU_STAGE(0); GU_STAGE(16384);
#pragma unroll 1
  for (int p = 0; p < 15; ++p) {
    VWAIT4; BAR; GU_COMPUTE(0);    BAR; GU_STAGE(0);
    VWAIT4; BAR; GU_COMPUTE(8192); BAR; GU_STAGE(16384);
  }
  VWAIT4; BAR; GU_COMPUTE(0);
  VWAIT0; BAR; GU_COMPUTE(8192);
#undef GU_STAGE
#undef GU_COMPUTE

#pragma unroll
  for (int i = 0; i < 4; i++) {
    int rowb = actbase + mb + 16 * i + quad * 4;
#pragma unroll
    for (int j = 0; j < 2; j++) {
      int col = n0 + nb + 16 * j + lr;
#pragma unroll
      for (int r = 0; r < 4; r++) {
        float h = accg[i][j][r];
        float u = accu[i][j][r];
        float a = h / (1.f + __expf(-h)) * u;
        act[(size_t)(rowb + r) * 1024 + col] = f2bf(a);
      }
    }
  }
}

// ---- down GEMM: 128m x 64n blocks, 4+ blocks/CU ----
__global__ __launch_bounds__(256, 4) void k_down(
    const unsigned short* __restrict__ act, const unsigned short* __restrict__ downT,
    const unsigned short* __restrict__ shDT, unsigned short* __restrict__ yslot,
    float* __restrict__ part, const int* __restrict__ tile_expert,
    const int* __restrict__ n_tiles) {
  int o = blockIdx.x;
  int wk = (o & 7) * (2 * GRID_Y) + (o >> 3);
  int nx = wk & 15, bt = wk >> 4;
  int NT = n_tiles[0];
  bool routed = bt < NT;
  const unsigned short* B;
  size_t bstride;
  int abase, obase, se = 0;
  if (routed) {
    int e = tile_expert[bt];
    B = downT + ((size_t)e << 20);
    bstride = 1024;
    abase = bt * 128;
    obase = bt * 128;
  } else {
    int st = bt - NT;
    if (st >= SH_TILES) return;
    se = st >> 4;
    int tt = st & 15;
    B = shDT + se * 1024;
    bstride = 2048;
    abase = ABASE_SH + se * T_TOK + tt * 128;
    obase = tt * 128;
  }
  int n0 = nx * 64;

  // [2 bufs][A(8KB) | B(4KB)] = 24 KB total
  __shared__ unsigned short lds[2 * 6144];

  int tid = threadIdx.x;
  int w = tid >> 6, L = tid & 63;
  int c0 = w * 128 + L, c1 = c0 + 64;
  int ar0 = c0 >> 2, ar1 = c1 >> 2;
  int ch0 = (c0 & 3) ^ (ar0 & 3), ch1 = (c1 & 3) ^ (ar1 & 3);
  int arb = tid >> 2;
  int chb = (tid & 3) ^ (arb & 3);
  const char* aA = (const char*)(act + (size_t)(abase + ar0) * 1024) + ch0 * 16;
  const char* aB = (const char*)(act + (size_t)(abase + ar1) * 1024) + ch1 * 16;
  const char* bA = (const char*)(B + (size_t)(n0 + arb) * bstride) + chb * 16;
  const int a0o = w * 2048, a1o = w * 2048 + 1024;
  const int bBo = 8192 + w * 1024;

  f32x4_t acc[4][2];
#pragma unroll
  for (int i = 0; i < 4; i++)
#pragma unroll
    for (int j = 0; j < 2; j++) acc[i][j] = f32x4_t{0.f, 0.f, 0.f, 0.f};

  int mb = (w >> 1) * 64, nb = (w & 1) * 32;
  int lr = L & 15, quad = L >> 4;
  int sw = ((quad ^ (lr & 3)) << 3);

#define DN_STAGE(BOFF)                                                       \
  { char* bp = (char*)lds + (BOFF);                                          \
    gld16(aA, bp + a0o); gld16(aB, bp + a1o);                                \
    gld16(bA, bp + bBo);                                                     \
    aA += 64; aB += 64; bA += 64; }

#define DN_COMPUTE(UOFF)                                                     \
  { const unsigned short* pA = lds + (UOFF);                                 \
    const unsigned short* pB = pA + 4096;                                    \
    bf16x8_t af[4], bb[2];                                                   \
    _Pragma("unroll")                                                        \
    for (int i = 0; i < 4; i++) af[i] = *(const bf16x8_t*)(pA + (mb + 16 * i + lr) * 32 + sw); \
    _Pragma("unroll")                                                        \
    for (int j = 0; j < 2; j++) bb[j] = *(const bf16x8_t*)(pB + (nb + 16 * j + lr) * 32 + sw); \
    __builtin_amdgcn_s_setprio(1);                                           \
    _Pragma("unroll")                                                        \
    for (int i = 0; i < 4; i++)                                              \
      _Pragma("unroll")                                                      \
      for (int j = 0; j < 2; j++)                                            \
        acc[i][j] = __builtin_amdgcn_mfma_f32_16x16x32_bf16(af[i], bb[j], acc[i][j], 0, 0, 0); \
    __builtin_amdgcn_s_setprio(0); }

  DN_STAGE(0); DN_STAGE(12288);
#pragma unroll 1
  for (int p = 0; p < 15; ++p) {
    VWAIT3; BAR; DN_COMPUTE(0);    BAR; DN_STAGE(0);
    VWAIT3; BAR; DN_COMPUTE(6144); BAR; DN_STAGE(12288);
  }
  VWAIT3; BAR; DN_COMPUTE(0);
  VWAIT0; BAR; DN_COMPUTE(6144);
#undef DN_STAGE
#undef DN_COMPUTE

#pragma unroll
  for (int i = 0; i < 4; i++) {
    int rowb = obase + mb + 16 * i + quad * 4;
#pragma unroll
    for (int j = 0; j < 2; j++) {
      int col = n0 + nb + 16 * j + lr;
#pragma unroll
      for (int r = 0; r < 4; r++) {
        float v = acc[i][j][r];
        if (routed) yslot[(size_t)(rowb + r) * 1024 + col] = f2bf(v);
        else part[(size_t)se * (T_TOK * 1024) + (size_t)(rowb + r) * 1024 + col] = v;
      }
    }
  }
}

// ---- final gather: out = part0 + part1 + sum_k w_k * yslot[slot_k] ----
__global__ void k_gather(float* __restrict__ out, const float* __restrict__ partial,
                         const unsigned short* __restrict__ yslot,
                         const int* __restrict__ tk_slot, const float* __restrict__ topk_w) {
  int t = blockIdx.x, tid = threadIdx.x;
  int4 sl = ((const int4*)tk_slot)[t];
  float4 wv = ((const float4*)topk_w)[t];
  int d = 4 * tid;
  float4 p0 = *(const float4*)(partial + (size_t)t * 1024 + d);
  float4 p1 = *(const float4*)(partial + (size_t)(T_TOK * 1024) + (size_t)t * 1024 + d);
  float4 o = {p0.x + p1.x, p0.y + p1.y, p0.z + p1.z, p0.w + p1.w};
  const int s[4] = {sl.x, sl.y, sl.z, sl.w};
  const float wk[4] = {wv.x, wv.y, wv.z, wv.w};
#pragma unroll
  for (int k = 0; k < 4; k++) {
    ushort4_t y = *(const ushort4_t*)(yslot + (size_t)s[k] * 1024 + d);
    o.x += wk[k] * bf2f(y[0]);
    o.y += wk[k] * bf2f(y[1]);
    o.z += wk[k] * bf2f(y[2]);
    o.w += wk[k] * bf2f(y[3]);
  }
  *(float4*)(out + (size_t)t * 1024 + d) = o;
}

extern "C" void kernel_launch(void* const* d_in, const int* in_sizes, int n_in,
                              void* d_out, int out_size, void* d_ws, size_t ws_size,
                              hipStream_t stream) {
  const float* x = (const float*)d_in[0];
  const float* rw = (const float*)d_in[1];
  const float* bias = (const float*)d_in[2];
  const float* gw = (const float*)d_in[3];
  const float* uw = (const float*)d_in[4];
  const float* dw = (const float*)d_in[5];
  const float* sg = (const float*)d_in[6];
  const float* su = (const float*)d_in[7];
  const float* sd = (const float*)d_in[8];
  float* out = (float*)d_out;
  char* ws = (char*)d_ws;

  unsigned short* xb    = (unsigned short*)(ws + OFF_XB);
  unsigned short* shGT  = (unsigned short*)(ws + OFF_SHGT);
  unsigned short* shUT  = (unsigned short*)(ws + OFF_SHUT);
  unsigned short* gateT = (unsigned short*)(ws + OFF_GATET);
  unsigned short* upT   = (unsigned short*)(ws + OFF_UPT);
  unsigned short* downT = (unsigned short*)(ws + OFF_DOWNT);
  unsigned short* shDT  = (unsigned short*)(ws + OFF_SHDT);
  unsigned short* act   = (unsigned short*)(ws + OFF_ACT);
  unsigned short* yslot = (unsigned short*)(ws + OFF_YSLOT);
  float*          part  = (float*)(ws + OFF_PART);   // overlays xb/shGT/shUT/gateT-head
  char* ctrl = ws + OFF_CTRL;
  int* offsets_    = (int*)(ctrl + CT_OFFSETS);
  int* n_tiles     = (int*)(ctrl + CT_NTILES);
  int* tile_expert = (int*)(ctrl + CT_TILEEXP);
  int* slot_token  = (int*)(ctrl + CT_SLOTTOK);
  int* tk_slot     = (int*)(ctrl + CT_TKSLOT);
  int* topk_idx    = (int*)(ctrl + CT_TOPKIDX);
  float* topk_w    = (float*)(ctrl + CT_TOPKW);

  k_transpose3<<<dim3(8, 8, 48), 256, 0, stream>>>(gw, uw, dw, gateT, upT, downT);
  k_transpose_sh<<<dim3(16, 8, 2), 256, 0, stream>>>(sg, su, shGT, shUT);
  k_transpose<<<dim3(8, 16, 1), 256, 0, stream>>>(sd, shDT, 2048, 1024);
  k_router<<<2048, 256, 0, stream>>>(x, rw, bias, topk_idx, topk_w, xb);
  k_route_post<<<1, 256, 0, stream>>>(topk_idx, offsets_, tile_expert, n_tiles,
                                      slot_token, tk_slot);
  // fused gate+up+silu for routed + shared "experts" (XCD-swizzled 1D grid)
  k_gateup<<<NBLK2, 256, 0, stream>>>(xb, gateT, upT, shGT, shUT, act,
                                      slot_token, tile_expert, n_tiles);
  // down for routed (-> yslot bf16) + shared (-> fp32 partial slabs)
  k_down<<<NBLK2, 256, 0, stream>>>(act, downT, shDT, yslot, part,
                                    tile_expert, n_tiles);
  // out = p0+p1 + weighted routed
  k_gather<<<2048, 256, 0, stream>>>(out, part, yslot, tk_slot, topk_w);
}

// Round 11
// 406.669 us; speedup vs baseline: 1.0641x; 1.0641x over previous
//
#include <hip/hip_runtime.h>
#include <cstdint>
#include <cstddef>

// DeepseekV3 MoE on gfx950.
// R10->R11: R10 (transpose-free, counted-vmcnt reg-pipelined B-staging)
// FAILED the determinism tripwire -- a timing-dependent race in the
// single-barrier interleave (3 tiles of state in flight across recycled
// registers + post-barrier ds_writes; not verifiable by inspection).
// R7/R8 showed schedule micro-opts buy ~0us here, so: KEEP the structural
// win (no transpose kernels; fp32 weights consumed in natural [K][N]
// layout, cvt+transpose fused into B-staging via reg->ds_write with the
// fragment-layout slot-XOR verified in R10), REVERT the K-loop to the
// R6-proven race-free form: per iter { BWRITE(nxt, regs from last iter);
// AG(nxt); BLOAD(t+2); COMPUTE(cur); __syncthreads() }. One full-drain
// barrier per iter; every cross-wave and reg dependency is barrier- or
// drain-separated. B prefetch still issues one compute-phase early.
// Net vs R9: -118us transposes, -330MB HBM traffic, launches 8 -> 5;
// GEMMs pay fp32 B reads (+~50us combined).

#define T_TOK 2048
#define DIM   1024
#define NEXP  16
#define MAXTILES 80
#define SH_TILES 32
#define GRID_Y (MAXTILES + SH_TILES)
#define NBLK (8 * GRID_Y)        // 896 = 8 XCDs * 112
#define ABASE_SH 10240           // act row where shared-expert rows start

typedef __bf16 bf16x8_t __attribute__((ext_vector_type(8)));
typedef float  f32x4_t  __attribute__((ext_vector_type(4)));
typedef unsigned short ushort8_t __attribute__((ext_vector_type(8)));
typedef unsigned short ushort4_t __attribute__((ext_vector_type(4)));

// ---- workspace layout (bytes) ----
#define OFF_XB     (0UL)            // 4 MB bf16 x
#define OFF_PART   (16UL<<20)       // 16 MB fp32 2 slabs
#define OFF_ACT    (112UL<<20)      // 28 MB  (14336 rows x 1024 bf16)
#define OFF_YSLOT  (140UL<<20)      // 20 MB  (10240 rows x 1024 bf16)
#define OFF_CTRL   (160UL<<20)
#define CT_OFFSETS  128
#define CT_NTILES   192
#define CT_TILEEXP  256
#define CT_SLOTTOK  4096
#define CT_TKSLOT   49152
#define CT_TOPKIDX  81920
#define CT_TOPKW    114688

__device__ __forceinline__ unsigned short f2bf(float f) {
  __bf16 h = (__bf16)f;
  return __builtin_bit_cast(unsigned short, h);
}
__device__ __forceinline__ float bf2f(unsigned short u) {
  unsigned int v = ((unsigned int)u) << 16;
  return __builtin_bit_cast(float, v);
}
__device__ __forceinline__ void gld16(const void* g, void* l) {
  __builtin_amdgcn_global_load_lds(
      (const __attribute__((address_space(1))) void*)(g),
      (__attribute__((address_space(3))) void*)(l), 16, 0, 0);
}

// ---- router: 1 block per token; also emits xb (bf16 x) ----
__global__ __launch_bounds__(256) void k_router(
    const float* __restrict__ x, const float* __restrict__ rw,
    const float* __restrict__ bias, int* __restrict__ topk_idx,
    float* __restrict__ topk_w, unsigned short* __restrict__ xb) {
  int t = blockIdx.x, tid = threadIdx.x;
  int wv = tid >> 6, lane = tid & 63;
  float4 xv = ((const float4*)(x + (size_t)t * DIM))[tid];
  ushort4_t xo;
  xo[0] = f2bf(xv.x); xo[1] = f2bf(xv.y); xo[2] = f2bf(xv.z); xo[3] = f2bf(xv.w);
  ((ushort4_t*)(xb + (size_t)t * DIM))[tid] = xo;
  float part[NEXP];
#pragma unroll
  for (int e = 0; e < NEXP; e++) {
    float4 wr = ((const float4*)(rw + (size_t)e * DIM))[tid];
    part[e] = xv.x * wr.x + xv.y * wr.y + xv.z * wr.z + xv.w * wr.w;
  }
  __shared__ float wsum_s[4 * NEXP];
#pragma unroll
  for (int e = 0; e < NEXP; e++) {
    float v = part[e];
#pragma unroll
    for (int off = 32; off; off >>= 1) v += __shfl_xor(v, off, 64);
    if (lane == 0) wsum_s[wv * NEXP + e] = v;
  }
  __syncthreads();
  if (tid == 0) {
    float r_sc[NEXP], r_s[NEXP];
#pragma unroll
    for (int e = 0; e < NEXP; e++) {
      float logit = wsum_s[e] + wsum_s[NEXP + e] + wsum_s[2 * NEXP + e] +
                    wsum_s[3 * NEXP + e];
      float sc = 1.f / (1.f + expf(-logit));
      r_sc[e] = sc;
      r_s[e] = sc + bias[e];
    }
    float gs[4];
#pragma unroll
    for (int g = 0; g < 4; g++) {
      float m1 = -1e30f, m2 = -1e30f;
#pragma unroll
      for (int j = 0; j < 4; j++) {
        float v = r_s[g * 4 + j];
        if (v > m1) { m2 = m1; m1 = v; } else if (v > m2) m2 = v;
      }
      gs[g] = m1 + m2;
    }
    int g1 = 0;
    for (int g = 1; g < 4; g++) if (gs[g] > gs[g1]) g1 = g;
    int g2 = -1;
    for (int g = 0; g < 4; g++) { if (g == g1) continue; if (g2 < 0 || gs[g] > gs[g2]) g2 = g; }
    int taken = 0, idx[4];
    float w[4], wsum = 1e-20f;
#pragma unroll
    for (int k = 0; k < 4; k++) {
      float best = -1e30f; int bi = 0;
#pragma unroll
      for (int e2 = 0; e2 < 16; e2++) {
        if (taken & (1 << e2)) continue;
        int g = e2 >> 2;
        float v = (g == g1 || g == g2) ? r_s[e2] : -1.f;
        if (v > best) { best = v; bi = e2; }
      }
      taken |= 1 << bi; idx[k] = bi;
    }
#pragma unroll
    for (int k = 0; k < 4; k++) { w[k] = r_sc[idx[k]]; wsum += w[k]; }
    float sc2 = 2.5f / wsum;
#pragma unroll
    for (int k = 0; k < 4; k++) {
      topk_idx[t * 4 + k] = idx[k];
      topk_w[t * 4 + k] = w[k] * sc2;
    }
  }
}

// ---- route_post: single block, atomic-free count + scan + scatter ----
__global__ __launch_bounds__(256) void k_route_post(
    const int* __restrict__ topk_idx, int* __restrict__ offsets,
    int* __restrict__ tile_expert, int* __restrict__ n_tiles,
    int* __restrict__ slot_token, int* __restrict__ tk_slot) {
  __shared__ int cnt[NEXP][257];
  __shared__ int offs[NEXP], tot[NEXP];
  int tid = threadIdx.x;
  int4 ent[8];
#pragma unroll
  for (int i = 0; i < 8; i++) ent[i] = ((const int4*)topk_idx)[tid * 8 + i];
  int lc[NEXP];
#pragma unroll
  for (int j = 0; j < NEXP; j++) lc[j] = 0;
#pragma unroll
  for (int i = 0; i < 8; i++) {
    int es[4] = {ent[i].x, ent[i].y, ent[i].z, ent[i].w};
#pragma unroll
    for (int k = 0; k < 4; k++)
#pragma unroll
      for (int j = 0; j < NEXP; j++) lc[j] += (es[k] == j) ? 1 : 0;
  }
#pragma unroll
  for (int j = 0; j < NEXP; j++) cnt[j][tid] = lc[j];
  __syncthreads();
  if (tid < NEXP) {
    int base = 0;
    for (int c = 0; c < 256; c += 8) {
      int v[8];
#pragma unroll
      for (int i = 0; i < 8; i++) v[i] = cnt[tid][c + i];
#pragma unroll
      for (int i = 0; i < 8; i++) { cnt[tid][c + i] = base; base += v[i]; }
    }
    tot[tid] = base;
  }
  __syncthreads();
  if (tid == 0) {
    int cum = 0, tt = 0;
    for (int e = 0; e < NEXP; e++) {
      offs[e] = cum;
      offsets[e] = cum;
      int nt = (tot[e] + 127) >> 7;
      for (int i = 0; i < nt; i++) tile_expert[tt++] = e;
      cum += nt << 7;
    }
    n_tiles[0] = tt;
  }
  __syncthreads();
  for (int e = 0; e < NEXP; e++) {
    int s0 = offs[e] + tot[e];
    int s1 = offs[e] + (((tot[e] + 127) >> 7) << 7);
    for (int s = s0 + tid; s < s1; s += 256) slot_token[s] = -1;
  }
  int lcur[NEXP];
#pragma unroll
  for (int j = 0; j < NEXP; j++) lcur[j] = offs[j] + cnt[j][tid];
#pragma unroll
  for (int i = 0; i < 8; i++) {
    int t = tid * 8 + i;
    int es[4] = {ent[i].x, ent[i].y, ent[i].z, ent[i].w};
#pragma unroll
    for (int k = 0; k < 4; k++) {
      int e = es[k], pos = 0;
#pragma unroll
      for (int j = 0; j < NEXP; j++) pos += (e == j) ? lcur[j] : 0;
#pragma unroll
      for (int j = 0; j < NEXP; j++) lcur[j] += (e == j) ? 1 : 0;
      slot_token[pos] = t;
      tk_slot[t * 4 + k] = pos;
    }
  }
}

// ---- fused gate+up+silu GEMM; B = fp32 natural [K][N], cvt fused ----
// grid 896 XCD-swizzled. Block 128m x 128n, 4 waves (64x64 each), K32 steps.
// LDS buf = A(8KB bf16, gld16) | Bg(8KB) | Bu(8KB) staged via reg+cvt.
// R6-style race-free loop: stage(nxt) then compute(cur), ONE __syncthreads
// per iter (full drain -- verifiably correct; schedule micro-opts were ~0).
__global__ __launch_bounds__(256, 2) void k_gateup(
    const unsigned short* __restrict__ xb, const float* __restrict__ gw,
    const float* __restrict__ uw, const float* __restrict__ sg,
    const float* __restrict__ su, unsigned short* __restrict__ act,
    const int* __restrict__ slot_token, const int* __restrict__ tile_expert,
    const int* __restrict__ n_tiles) {
  int o = blockIdx.x;
  int wk = (o & 7) * GRID_Y + (o >> 3);   // bijective XCD swizzle
  int nx = wk & 7, bt = wk >> 3;
  int NT = n_tiles[0];
  bool routed = bt < NT;
  const float *Bg, *Bu;
  size_t sN;
  int actbase, tokbase = 0;
  if (routed) {
    int e = tile_expert[bt];
    Bg = gw + ((size_t)e << 20);
    Bu = uw + ((size_t)e << 20);
    sN = 1024;
    actbase = bt * 128;
  } else {
    int st = bt - NT;
    if (st >= SH_TILES) return;
    int se = st >> 4, tt = st & 15;
    Bg = sg + se * 1024;
    Bu = su + se * 1024;
    sN = 2048;
    actbase = ABASE_SH + se * T_TOK + tt * 128;
    tokbase = tt * 128;
  }
  int n0 = nx * 128;

  // [2 bufs][A | Bg | Bu] = 24 KB each -> 48 KB
  __shared__ unsigned short lds[2 * 12288];

  int tid = threadIdx.x;
  int w = tid >> 6, L = tid & 63;
  // A staging (gld16, bf16 source)
  int c0 = w * 128 + L, c1 = c0 + 64;
  int ar0 = c0 >> 2, ar1 = c1 >> 2;
  int ch0 = (c0 & 3) ^ (ar0 & 3), ch1 = (c1 & 3) ^ (ar1 & 3);
  long arow0, arow1;
  if (routed) {
    int t0 = slot_token[bt * 128 + ar0]; if (t0 < 0) t0 = 0;
    int t1 = slot_token[bt * 128 + ar1]; if (t1 < 0) t1 = 0;
    arow0 = t0; arow1 = t1;
  } else {
    arow0 = tokbase + ar0; arow1 = tokbase + ar1;
  }
  const char* aA = (const char*)(xb + arow0 * 1024) + ch0 * 16;
  const char* aB = (const char*)(xb + arow1 * 1024) + ch1 * 16;
  const int a0o = w * 2048, a1o = w * 2048 + 1024;

  // B staging: thread (g_ = tid>>5, m_ = tid&31): 4 consecutive k-rows
  // (4g_..4g_+3), n-cols 4m_..4m_+3; per-instr = two 512B segments.
  int g_ = tid >> 5, m_ = tid & 31;
  size_t sN4 = sN * 4;
  const char* pg_ = (const char*)(Bg + (size_t)(4 * g_) * sN + n0 + 4 * m_);
  const char* pu_ = (const char*)(Bu + (size_t)(4 * g_) * sN + n0 + 4 * m_);
  float4 rg[4], ru[4];

  f32x4_t accg[4][4], accu[4][4];
#pragma unroll
  for (int i = 0; i < 4; i++)
#pragma unroll
    for (int j = 0; j < 4; j++) {
      accg[i][j] = f32x4_t{0.f, 0.f, 0.f, 0.f};
      accu[i][j] = f32x4_t{0.f, 0.f, 0.f, 0.f};
    }

  int mb = (w >> 1) * 64, nb = (w & 1) * 64;
  int lr = L & 15, quad = L >> 4;
  int swA = ((quad ^ (lr & 3)) << 3);
  int swB = ((quad ^ (lr & 3) ^ ((lr >> 2) & 3)) << 3);

#define GU_BLOAD {                                                           \
    rg[0] = *(const float4*)(pg_);           rg[1] = *(const float4*)(pg_ + sN4); \
    rg[2] = *(const float4*)(pg_ + 2 * sN4); rg[3] = *(const float4*)(pg_ + 3 * sN4); \
    ru[0] = *(const float4*)(pu_);           ru[1] = *(const float4*)(pu_ + sN4); \
    ru[2] = *(const float4*)(pu_ + 2 * sN4); ru[3] = *(const float4*)(pu_ + 3 * sN4); \
    pg_ += 32 * sN4; pu_ += 32 * sN4; }

#define GU_AG(BOFF) {                                                        \
    char* bp = (char*)lds + (BOFF);                                          \
    gld16(aA, bp + a0o); gld16(aB, bp + a1o);                                \
    aA += 64; aB += 64; }

// write 4 bf16 along k per b64; slot = chunk ^ (n&3) ^ ((n>>2)&3)
#define GU_BWRITE(BOFF) {                                                    \
    char* bgp = (char*)lds + (BOFF) + 8192;                                  \
    char* bup = (char*)lds + (BOFF) + 16384;                                 \
    _Pragma("unroll")                                                        \
    for (int j = 0; j < 4; j++) {                                            \
      int row = 4 * m_ + j;                                                  \
      int slot = (g_ >> 1) ^ j ^ (m_ & 3);                                   \
      int off = row * 64 + slot * 16 + (g_ & 1) * 8;                         \
      ushort4_t pgv, puv;                                                    \
      pgv[0] = f2bf(rg[0][j]); pgv[1] = f2bf(rg[1][j]);                      \
      pgv[2] = f2bf(rg[2][j]); pgv[3] = f2bf(rg[3][j]);                      \
      puv[0] = f2bf(ru[0][j]); puv[1] = f2bf(ru[1][j]);                      \
      puv[2] = f2bf(ru[2][j]); puv[3] = f2bf(ru[3][j]);                      \
      *(ushort4_t*)(bgp + off) = pgv;                                        \
      *(ushort4_t*)(bup + off) = puv;                                        \
    } }

#define GU_COMPUTE(UOFF) {                                                   \
    const unsigned short* pA = lds + (UOFF);                                 \
    const unsigned short* pG = pA + 4096;                                    \
    const unsigned short* pU = pA + 8192;                                    \
    bf16x8_t af[4], bg[4], bu[4];                                            \
    _Pragma("unroll")                                                        \
    for (int i = 0; i < 4; i++) af[i] = *(const bf16x8_t*)(pA + (mb + 16 * i + lr) * 32 + swA); \
    _Pragma("unroll")                                                        \
    for (int i = 0; i < 4; i++) bg[i] = *(const bf16x8_t*)(pG + (nb + 16 * i + lr) * 32 + swB); \
    _Pragma("unroll")                                                        \
    for (int i = 0; i < 4; i++) bu[i] = *(const bf16x8_t*)(pU + (nb + 16 * i + lr) * 32 + swB); \
    _Pragma("unroll")                                                        \
    for (int i = 0; i < 4; i++)                                              \
      _Pragma("unroll")                                                      \
      for (int j = 0; j < 4; j++) {                                          \
        accg[i][j] = __builtin_amdgcn_mfma_f32_16x16x32_bf16(af[i], bg[j], accg[i][j], 0, 0, 0); \
        accu[i][j] = __builtin_amdgcn_mfma_f32_16x16x32_bf16(af[i], bu[j], accu[i][j], 0, 0, 0); \
      } }

  // prologue: tile0 fully staged into buf0; B(1) regs in flight
  GU_BLOAD;                 // B(0) -> regs
  GU_BWRITE(0);             // buf0 B (compiler waits the loads)
  GU_AG(0);                 // buf0 A
  GU_BLOAD;                 // B(1) -> regs
  __syncthreads();          // full drain: buf0 complete, B(1) regs complete
#pragma unroll 1
  for (int t = 0; t < 32; ++t) {
    int cur = t & 1;
    if (t < 31) {
      GU_BWRITE(cur ? 0 : 24576);   // nxt buf <- B(t+1) regs (drained)
      GU_AG(cur ? 0 : 24576);       // nxt buf <- A(t+1)
      if (t < 30) GU_BLOAD;         // B(t+2) -> regs
    }
    GU_COMPUTE(cur ? 12288 : 0);
    __syncthreads();
  }
#undef GU_BLOAD
#undef GU_AG
#undef GU_BWRITE
#undef GU_COMPUTE

#pragma unroll
  for (int i = 0; i < 4; i++) {
    int rowb = actbase + mb + 16 * i + quad * 4;
#pragma unroll
    for (int j = 0; j < 4; j++) {
      int col = n0 + nb + 16 * j + lr;
#pragma unroll
      for (int r = 0; r < 4; r++) {
        float h = accg[i][j][r];
        float u = accu[i][j][r];
        float a = h / (1.f + __expf(-h)) * u;
        act[(size_t)(rowb + r) * 1024 + col] = f2bf(a);
      }
    }
  }
}

// ---- down GEMM; B = fp32 natural [K=F][N=D], cvt fused ----
__global__ __launch_bounds__(256, 2) void k_down(
    const unsigned short* __restrict__ act, const float* __restrict__ dw,
    const float* __restrict__ sd, unsigned short* __restrict__ yslot,
    float* __restrict__ part, const int* __restrict__ tile_expert,
    const int* __restrict__ n_tiles) {
  int o = blockIdx.x;
  int wk = (o & 7) * GRID_Y + (o >> 3);
  int nx = wk & 7, bt = wk >> 3;
  int NT = n_tiles[0];
  bool routed = bt < NT;
  const float* B;
  int abase, obase, se = 0;
  if (routed) {
    int e = tile_expert[bt];
    B = dw + ((size_t)e << 20);
    abase = bt * 128;
    obase = bt * 128;
  } else {
    int st = bt - NT;
    if (st >= SH_TILES) return;
    se = st >> 4;
    int tt = st & 15;
    B = sd + (size_t)se * 1024 * 1024;
    abase = ABASE_SH + se * T_TOK + tt * 128;
    obase = tt * 128;
  }
  const size_t sN = 1024;
  int n0 = nx * 128;

  // [2 bufs][A | B] = 16 KB each -> 32 KB
  __shared__ unsigned short lds[2 * 8192];

  int tid = threadIdx.x;
  int w = tid >> 6, L = tid & 63;
  int c0 = w * 128 + L, c1 = c0 + 64;
  int ar0 = c0 >> 2, ar1 = c1 >> 2;
  int ch0 = (c0 & 3) ^ (ar0 & 3), ch1 = (c1 & 3) ^ (ar1 & 3);
  const char* aA = (const char*)(act + (size_t)(abase + ar0) * 1024) + ch0 * 16;
  const char* aB = (const char*)(act + (size_t)(abase + ar1) * 1024) + ch1 * 16;
  const int a0o = w * 2048, a1o = w * 2048 + 1024;

  int g_ = tid >> 5, m_ = tid & 31;
  const size_t sN4 = sN * 4;
  const char* pb_ = (const char*)(B + (size_t)(4 * g_) * sN + n0 + 4 * m_);
  float4 rb[4];

  f32x4_t acc[4][4];
#pragma unroll
  for (int i = 0; i < 4; i++)
#pragma unroll
    for (int j = 0; j < 4; j++) acc[i][j] = f32x4_t{0.f, 0.f, 0.f, 0.f};

  int mb = (w >> 1) * 64, nb = (w & 1) * 64;
  int lr = L & 15, quad = L >> 4;
  int swA = ((quad ^ (lr & 3)) << 3);
  int swB = ((quad ^ (lr & 3) ^ ((lr >> 2) & 3)) << 3);

#define DN_BLOAD {                                                           \
    rb[0] = *(const float4*)(pb_);           rb[1] = *(const float4*)(pb_ + sN4); \
    rb[2] = *(const float4*)(pb_ + 2 * sN4); rb[3] = *(const float4*)(pb_ + 3 * sN4); \
    pb_ += 32 * sN4; }

#define DN_AG(BOFF) {                                                        \
    char* bp = (char*)lds + (BOFF);                                          \
    gld16(aA, bp + a0o); gld16(aB, bp + a1o);                                \
    aA += 64; aB += 64; }

#define DN_BWRITE(BOFF) {                                                    \
    char* bbp = (char*)lds + (BOFF) + 8192;                                  \
    _Pragma("unroll")                                                        \
    for (int j = 0; j < 4; j++) {                                            \
      int row = 4 * m_ + j;                                                  \
      int slot = (g_ >> 1) ^ j ^ (m_ & 3);                                   \
      int off = row * 64 + slot * 16 + (g_ & 1) * 8;                         \
      ushort4_t pv;                                                          \
      pv[0] = f2bf(rb[0][j]); pv[1] = f2bf(rb[1][j]);                        \
      pv[2] = f2bf(rb[2][j]); pv[3] = f2bf(rb[3][j]);                        \
      *(ushort4_t*)(bbp + off) = pv;                                         \
    } }

#define DN_COMPUTE(UOFF) {                                                   \
    const unsigned short* pA = lds + (UOFF);                                 \
    const unsigned short* pB = pA + 4096;                                    \
    bf16x8_t af[4], bb[4];                                                   \
    _Pragma("unroll")                                                        \
    for (int i = 0; i < 4; i++) af[i] = *(const bf16x8_t*)(pA + (mb + 16 * i + lr) * 32 + swA); \
    _Pragma("unroll")                                                        \
    for (int i = 0; i < 4; i++) bb[i] = *(const bf16x8_t*)(pB + (nb + 16 * i + lr) * 32 + swB); \
    _Pragma("unroll")                                                        \
    for (int i = 0; i < 4; i++)                                              \
      _Pragma("unroll")                                                      \
      for (int j = 0; j < 4; j++)                                            \
        acc[i][j] = __builtin_amdgcn_mfma_f32_16x16x32_bf16(af[i], bb[j], acc[i][j], 0, 0, 0); }

  DN_BLOAD;                 // B(0)
  DN_BWRITE(0);             // buf0 B
  DN_AG(0);                 // buf0 A
  DN_BLOAD;                 // B(1)
  __syncthreads();
#pragma unroll 1
  for (int t = 0; t < 32; ++t) {
    int cur = t & 1;
    if (t < 31) {
      DN_BWRITE(cur ? 0 : 16384);
      DN_AG(cur ? 0 : 16384);
      if (t < 30) DN_BLOAD;
    }
    DN_COMPUTE(cur ? 8192 : 0);
    __syncthreads();
  }
#undef DN_BLOAD
#undef DN_AG
#undef DN_BWRITE
#undef DN_COMPUTE

#pragma unroll
  for (int i = 0; i < 4; i++) {
    int rowb = obase + mb + 16 * i + quad * 4;
#pragma unroll
    for (int j = 0; j < 4; j++) {
      int col = n0 + nb + 16 * j + lr;
#pragma unroll
      for (int r = 0; r < 4; r++) {
        float v = acc[i][j][r];
        if (routed) yslot[(size_t)(rowb + r) * 1024 + col] = f2bf(v);
        else part[(size_t)se * (T_TOK * 1024) + (size_t)(rowb + r) * 1024 + col] = v;
      }
    }
  }
}

// ---- final gather: out = part0 + part1 + sum_k w_k * yslot[slot_k] ----
__global__ void k_gather(float* __restrict__ out, const float* __restrict__ partial,
                         const unsigned short* __restrict__ yslot,
                         const int* __restrict__ tk_slot, const float* __restrict__ topk_w) {
  int t = blockIdx.x, tid = threadIdx.x;
  int4 sl = ((const int4*)tk_slot)[t];
  float4 wv = ((const float4*)topk_w)[t];
  int d = 4 * tid;
  float4 p0 = *(const float4*)(partial + (size_t)t * 1024 + d);
  float4 p1 = *(const float4*)(partial + (size_t)(T_TOK * 1024) + (size_t)t * 1024 + d);
  float4 o = {p0.x + p1.x, p0.y + p1.y, p0.z + p1.z, p0.w + p1.w};
  const int s[4] = {sl.x, sl.y, sl.z, sl.w};
  const float wk[4] = {wv.x, wv.y, wv.z, wv.w};
#pragma unroll
  for (int k = 0; k < 4; k++) {
    ushort4_t y = *(const ushort4_t*)(yslot + (size_t)s[k] * 1024 + d);
    o.x += wk[k] * bf2f(y[0]);
    o.y += wk[k] * bf2f(y[1]);
    o.z += wk[k] * bf2f(y[2]);
    o.w += wk[k] * bf2f(y[3]);
  }
  *(float4*)(out + (size_t)t * 1024 + d) = o;
}

extern "C" void kernel_launch(void* const* d_in, const int* in_sizes, int n_in,
                              void* d_out, int out_size, void* d_ws, size_t ws_size,
                              hipStream_t stream) {
  const float* x = (const float*)d_in[0];
  const float* rw = (const float*)d_in[1];
  const float* bias = (const float*)d_in[2];
  const float* gw = (const float*)d_in[3];
  const float* uw = (const float*)d_in[4];
  const float* dw = (const float*)d_in[5];
  const float* sg = (const float*)d_in[6];
  const float* su = (const float*)d_in[7];
  const float* sd = (const float*)d_in[8];
  float* out = (float*)d_out;
  char* ws = (char*)d_ws;

  unsigned short* xb    = (unsigned short*)(ws + OFF_XB);
  unsigned short* act   = (unsigned short*)(ws + OFF_ACT);
  unsigned short* yslot = (unsigned short*)(ws + OFF_YSLOT);
  float*          part  = (float*)(ws + OFF_PART);
  char* ctrl = ws + OFF_CTRL;
  int* offsets_    = (int*)(ctrl + CT_OFFSETS);
  int* n_tiles     = (int*)(ctrl + CT_NTILES);
  int* tile_expert = (int*)(ctrl + CT_TILEEXP);
  int* slot_token  = (int*)(ctrl + CT_SLOTTOK);
  int* tk_slot     = (int*)(ctrl + CT_TKSLOT);
  int* topk_idx    = (int*)(ctrl + CT_TOPKIDX);
  float* topk_w    = (float*)(ctrl + CT_TOPKW);

  k_router<<<2048, 256, 0, stream>>>(x, rw, bias, topk_idx, topk_w, xb);
  k_route_post<<<1, 256, 0, stream>>>(topk_idx, offsets_, tile_expert, n_tiles,
                                      slot_token, tk_slot);
  // fused gate+up+silu: fp32 weights consumed directly (cvt fused in staging)
  k_gateup<<<NBLK, 256, 0, stream>>>(xb, gw, uw, sg, su, act,
                                     slot_token, tile_expert, n_tiles);
  // down: fp32 weights consumed directly
  k_down<<<NBLK, 256, 0, stream>>>(act, dw, sd, yslot, part,
                                   tile_expert, n_tiles);
  // out = p0+p1 + weighted routed
  k_gather<<<2048, 256, 0, stream>>>(out, part, yslot, tk_slot, topk_w);
}